// Round 13
// baseline (159.648 us; speedup 1.0000x reference)
//
#include <hip/hip_runtime.h>
#include <cmath>

#define N_NODES 50000
#define N_EDGES 800000
#define N_FEAT 128
#define DIM 64
#define N_GRAPHS 512
#define GGRID ((N_NODES + 63) / 64)         // 782 gemm1 tiles / buckets
#define NBKT GGRID                          // bucket = dst>>6
#define BH_BLK 128                          // bucket-sort blocks
#define EPB (N_EDGES / BH_BLK)              // 6250 edges per sort block
#define NCNT (NBKT * BH_BLK)                // 100096 count-matrix entries
#define P2_NBLK ((NCNT + 511) / 512)        // 196 scan blocks (512 elems each)
#define BKT_CAP 2048                        // max bucket edges (mean 1024)

// gemm1 tile distribution across the four front dispatches
#define T_BHIST 262
#define T_PSUM  160
#define T_SBLK  160
#define T_BSCAT 200                         // 262+160+160+200 = 782

// bf16 storage helpers (RNE). Storage-only: all math in fp32.
__device__ __forceinline__ unsigned short f2bf(float f) {
  union { float f; unsigned int u; } v; v.f = f;
  return (unsigned short)((v.u + 0x7FFFu + ((v.u >> 16) & 1u)) >> 16);
}
__device__ __forceinline__ float bf2f(unsigned short u) {
  union { unsigned int u; float f; } v; v.u = (unsigned int)u << 16;
  return v.f;
}

// ---------------------------------------------------------------------------
// GEMM body for gemm1: out[M][64] = A[M][128] @ W[128][64], bf16 output rows.
template<int K>
__device__ __forceinline__ void gemm_body_bf(const float* __restrict__ A,
                                             const float* __restrict__ W,
                                             unsigned short* __restrict__ out,
                                             int M, int row0, int tid,
                                             float* sX, float* sW) {
  const int tx = tid & 15, ty = tid >> 4;
  const int q = tid & 7, r0 = tid >> 3;
  float acc[4][4] = {};

  for (int kb = 0; kb < K; kb += 32) {
    __syncthreads();
    if ((kb & 63) == 0) {
#pragma unroll
      for (int i = 0; i < 16; i++)
        sW[i * 256 + tid] = W[kb * 64 + i * 256 + tid];
    }
#pragma unroll
    for (int rr = 0; rr < 64; rr += 32) {
      int r = r0 + rr;
      int gr = row0 + r;
      float4 v = make_float4(0.f, 0.f, 0.f, 0.f);
      if (gr < M) v = *(const float4*)&A[(size_t)gr * K + kb + q * 4];
      *(float4*)&sX[r * 36 + q * 4] = v;
    }
    __syncthreads();

    const int kw = kb & 63;
#pragma unroll 4
    for (int k = 0; k < 32; k += 4) {
      float4 wv[4];
#pragma unroll
      for (int kk = 0; kk < 4; kk++)
        wv[kk] = *(const float4*)&sW[(kw + k + kk) * 64 + tx * 4];
#pragma unroll
      for (int r = 0; r < 4; r++) {
        float4 xv = *(const float4*)&sX[(ty * 4 + r) * 36 + k];
        const float xs[4] = {xv.x, xv.y, xv.z, xv.w};
#pragma unroll
        for (int kk = 0; kk < 4; kk++) {
          acc[r][0] += xs[kk] * wv[kk].x;
          acc[r][1] += xs[kk] * wv[kk].y;
          acc[r][2] += xs[kk] * wv[kk].z;
          acc[r][3] += xs[kk] * wv[kk].w;
        }
      }
    }
  }

#pragma unroll
  for (int r = 0; r < 4; r++) {
    int gr = row0 + ty * 4 + r;
    if (gr < M) {
      ushort4 u;
      u.x = f2bf(acc[r][0]); u.y = f2bf(acc[r][1]);
      u.z = f2bf(acc[r][2]); u.w = f2bf(acc[r][3]);
      *(ushort4*)&out[(size_t)gr * 64 + tx * 4] = u;
    }
  }
}

// ---------------------------------------------------------------------------
// dispatch 1: blocks [0,128) bucket histogram of dst>>6; block 128 = w2fc;
// blocks [129..) = gemm1 tiles [0,262).
__global__ __launch_bounds__(256) void f_bhist(const int* __restrict__ dst,
                                               int* __restrict__ cnt,
                                               const float* __restrict__ W2,
                                               const float* __restrict__ Wfc,
                                               float* __restrict__ w2fc,
                                               const float* __restrict__ x,
                                               const float* __restrict__ W1,
                                               unsigned short* __restrict__ h1) {
  __shared__ float sX[64 * 36];
  __shared__ float sW[64 * 64];
  const int tid = threadIdx.x;
  if (blockIdx.x >= BH_BLK + 1) {
    int tile = blockIdx.x - (BH_BLK + 1);           // [0, T_BHIST)
    gemm_body_bf<N_FEAT>(x, W1, h1, N_NODES, tile * 64, tid, sX, sW);
    return;
  }
  if (blockIdx.x == BH_BLK) {
    if (tid < 64) {
      float s = 0.f;
#pragma unroll 8
      for (int j = 0; j < 64; j++) s += W2[tid * 64 + j] * Wfc[j];
      w2fc[tid] = s;
    }
    return;
  }
  int* lh = (int*)sX;                               // 782 ints
  const int k = blockIdx.x;
  for (int i = tid; i < NBKT; i += 256) lh[i] = 0;
  __syncthreads();
  const int base = k * EPB;
  for (int j = tid; j < EPB; j += 256)
    atomicAdd(&lh[dst[base + j] >> 6], 1);
  __syncthreads();
  for (int i = tid; i < NBKT; i += 256) cnt[i * BH_BLK + k] = lh[i];
}

// ---------------------------------------------------------------------------
// dispatch 2: blocks [0,196) = per-512-chunk raw sums of cnt;
// blocks [196..) = gemm1 tiles [262,422).
__global__ __launch_bounds__(256) void f_psum(const int* __restrict__ cnt,
                                              int* __restrict__ partials,
                                              const float* __restrict__ x,
                                              const float* __restrict__ W1,
                                              unsigned short* __restrict__ h1) {
  __shared__ float sX[64 * 36];
  __shared__ float sW[64 * 64];
  const int tid = threadIdx.x;
  if (blockIdx.x >= P2_NBLK) {
    int tile = T_BHIST + (blockIdx.x - P2_NBLK);
    gemm_body_bf<N_FEAT>(x, W1, h1, N_NODES, tile * 64, tid, sX, sW);
    return;
  }
  int* ws = (int*)sX;                               // 4 wave sums
  const int2* cnt2 = (const int2*)cnt;
  int idx = blockIdx.x * 256 + tid;                 // pair index
  int v = 0;
  if (idx * 2 < NCNT) { int2 c = cnt2[idx]; v = c.x + c.y; }
#pragma unroll
  for (int off = 32; off; off >>= 1) v += __shfl_down(v, off, 64);
  int lane = tid & 63, w = tid >> 6;
  if (lane == 0) ws[w] = v;
  __syncthreads();
  if (tid == 0) partials[blockIdx.x] = ws[0] + ws[1] + ws[2] + ws[3];
}

// ---------------------------------------------------------------------------
// dispatch 3: blocks [0,196) = block-local scan of 512 cnt elems + redundant
// LDS scan of the 196 raw partials -> in-place exclusive offsets + bucket_ptr.
// blocks [196..) = gemm1 tiles [422,582).
__global__ __launch_bounds__(256) void f_sblocks(int* __restrict__ cnt,
                                                 const int* __restrict__ partials,
                                                 int* __restrict__ bucket_ptr,
                                                 const float* __restrict__ x,
                                                 const float* __restrict__ W1,
                                                 unsigned short* __restrict__ h1) {
  __shared__ float sX[64 * 36];
  __shared__ float sW[64 * 64];
  const int tid = threadIdx.x;
  if (blockIdx.x >= P2_NBLK) {
    int tile = T_BHIST + T_PSUM + (blockIdx.x - P2_NBLK);
    gemm_body_bf<N_FEAT>(x, W1, h1, N_NODES, tile * 64, tid, sX, sW);
    return;
  }
  int* buf  = (int*)sX;                             // 256 thread-pair sums
  int* pbuf = buf + 256;                            // 196-wide partials scan
  int2* cnt2 = (int2*)cnt;
  const int idx = blockIdx.x * 256 + tid;
  int2 c = make_int2(0, 0);
  if (idx * 2 < NCNT) c = cnt2[idx];
  int s = c.x + c.y;
  buf[tid] = s;
  pbuf[tid] = (tid < P2_NBLK) ? partials[tid] : 0;
  __syncthreads();
  for (int off = 1; off < 256; off <<= 1) {         // inclusive scans
    int t1 = (tid >= off) ? buf[tid - off] : 0;
    int t2 = (tid >= off) ? pbuf[tid - off] : 0;
    __syncthreads();
    buf[tid] += t1;
    pbuf[tid] += t2;
    __syncthreads();
  }
  const int thr_excl = buf[tid] - s;
  const int base = (blockIdx.x > 0) ? pbuf[blockIdx.x - 1] : 0;
  if (idx * 2 < NCNT) {
    int e0 = base + thr_excl;
    cnt2[idx] = make_int2(e0, e0 + c.x);            // exclusive offsets
    int p = idx * 2;
    if ((p & (BH_BLK - 1)) == 0) bucket_ptr[p >> 7] = e0;
    if (p + 1 == NCNT - 1) bucket_ptr[NBKT] = e0 + c.x + c.y;  // == N_EDGES
  }
}

// ---------------------------------------------------------------------------
// dispatch 4: blocks [0,128) = bucket-sorted edge scatter (packed
// (src<<6)|dst_local); blocks [128..) = gemm1 tiles [582,782).
__global__ __launch_bounds__(256) void f_bscatter(const int* __restrict__ src,
                                                  const int* __restrict__ dst,
                                                  const int* __restrict__ cnt,
                                                  unsigned int* __restrict__ ebuf,
                                                  const float* __restrict__ x,
                                                  const float* __restrict__ W1,
                                                  unsigned short* __restrict__ h1) {
  __shared__ float sX[64 * 36];
  __shared__ float sW[64 * 64];
  const int tid = threadIdx.x;
  if (blockIdx.x >= BH_BLK) {
    int tile = T_BHIST + T_PSUM + T_SBLK + (blockIdx.x - BH_BLK);
    gemm_body_bf<N_FEAT>(x, W1, h1, N_NODES, tile * 64, tid, sX, sW);
    return;
  }
  int* loff = (int*)sX;                             // 782 ints
  const int k = blockIdx.x;
  for (int i = tid; i < NBKT; i += 256) loff[i] = cnt[i * BH_BLK + k];
  __syncthreads();
  const int base = k * EPB;
  for (int j = tid; j < EPB; j += 256) {
    int e = base + j;
    int d = dst[e];
    int pos = atomicAdd(&loff[d >> 6], 1);
    ebuf[pos] = ((unsigned int)src[e] << 6) | (unsigned int)(d & 63);
  }
}

// ---------------------------------------------------------------------------
// dispatch 5: per-bucket LDS CSR sort + layer-1 gather + relu + dot(w2fc)
// -> z[node]. 782 blocks x 1024 threads (16 waves x 4 nodes).
__global__ __launch_bounds__(1024, 8) void gather_z_fused(
    const unsigned short* __restrict__ h1,
    const unsigned int* __restrict__ ebuf,
    const int* __restrict__ bucket_ptr,
    const float* __restrict__ w2fc,
    float* __restrict__ z) {
  __shared__ int colL[BKT_CAP];
  __shared__ int lstart[64];
  __shared__ int lcur[64];
  __shared__ float sw[64];
  const int tid = threadIdx.x;
  const int b = blockIdx.x;
  const int p0 = bucket_ptr[b];
  int cnt = bucket_ptr[b + 1] - p0;
  if (cnt > BKT_CAP) cnt = BKT_CAP;                 // never triggers

  if (tid < 64) { lstart[tid] = 0; sw[tid] = w2fc[tid]; }
  __syncthreads();
  for (int i = tid; i < cnt; i += 1024)
    atomicAdd(&lstart[ebuf[p0 + i] & 63], 1);
  __syncthreads();
  if (tid < 64) {
    int v = lstart[tid], s = v;
#pragma unroll
    for (int off = 1; off < 64; off <<= 1) {
      int t = __shfl_up(s, off, 64);
      if (tid >= off) s += t;
    }
    lstart[tid] = s - v;
    lcur[tid] = s - v;
  }
  __syncthreads();
  for (int i = tid; i < cnt; i += 1024) {
    unsigned int u = ebuf[p0 + i];
    int pos = atomicAdd(&lcur[u & 63], 1);
    colL[pos] = (int)(u >> 6);
  }
  __syncthreads();

  const int lane = tid & 63, w = tid >> 6;
  const int eo = lane >> 4, qfo = (lane & 15) << 2;
#pragma unroll
  for (int ni = 0; ni < 4; ni++) {
    const int r = ni * 16 + w;
    const int i1 = lcur[r];
    int i = lstart[r];
    float4 acc = make_float4(0.f, 0.f, 0.f, 0.f);
    for (; i + 16 <= i1; i += 16) {
      int s0 = colL[i + eo];
      int s1 = colL[i + 4 + eo];
      int s2 = colL[i + 8 + eo];
      int s3 = colL[i + 12 + eo];
      ushort4 u0 = *(const ushort4*)&h1[(size_t)s0 * 64 + qfo];
      ushort4 u1 = *(const ushort4*)&h1[(size_t)s1 * 64 + qfo];
      ushort4 u2 = *(const ushort4*)&h1[(size_t)s2 * 64 + qfo];
      ushort4 u3 = *(const ushort4*)&h1[(size_t)s3 * 64 + qfo];
      acc.x += (bf2f(u0.x) + bf2f(u1.x)) + (bf2f(u2.x) + bf2f(u3.x));
      acc.y += (bf2f(u0.y) + bf2f(u1.y)) + (bf2f(u2.y) + bf2f(u3.y));
      acc.z += (bf2f(u0.z) + bf2f(u1.z)) + (bf2f(u2.z) + bf2f(u3.z));
      acc.w += (bf2f(u0.w) + bf2f(u1.w)) + (bf2f(u2.w) + bf2f(u3.w));
    }
    for (; i + 4 <= i1; i += 4) {
      int s = colL[i + eo];
      ushort4 u = *(const ushort4*)&h1[(size_t)s * 64 + qfo];
      acc.x += bf2f(u.x); acc.y += bf2f(u.y);
      acc.z += bf2f(u.z); acc.w += bf2f(u.w);
    }
    if (eo < i1 - i) {
      int s = colL[i + eo];
      ushort4 u = *(const ushort4*)&h1[(size_t)s * 64 + qfo];
      acc.x += bf2f(u.x); acc.y += bf2f(u.y);
      acc.z += bf2f(u.z); acc.w += bf2f(u.w);
    }
#pragma unroll
    for (int m = 16; m <= 32; m <<= 1) {            // reduce over eo
      acc.x += __shfl_xor(acc.x, m, 64);
      acc.y += __shfl_xor(acc.y, m, 64);
      acc.z += __shfl_xor(acc.z, m, 64);
      acc.w += __shfl_xor(acc.w, m, 64);
    }
    float p = fmaxf(acc.x, 0.f) * sw[qfo] + fmaxf(acc.y, 0.f) * sw[qfo + 1] +
              fmaxf(acc.z, 0.f) * sw[qfo + 2] + fmaxf(acc.w, 0.f) * sw[qfo + 3];
#pragma unroll
    for (int m = 1; m <= 8; m <<= 1) p += __shfl_xor(p, m, 64);
    int node = b * 64 + r;
    if (lane == 0 && node < N_NODES) z[node] = p;
  }
}

// ---------------------------------------------------------------------------
// dispatch 6: per-graph Sum over EDGES whose dst lies in the graph's node
// range of z[src] (layer-2 aggregation collapsed); /count; sigmoid.
__global__ __launch_bounds__(256) void graph_pool(const float* __restrict__ z,
                                                  const unsigned int* __restrict__ ebuf,
                                                  const int* __restrict__ bucket_ptr,
                                                  const int* __restrict__ batch,
                                                  float* __restrict__ out) {
  __shared__ float sacc[4];
  int g = blockIdx.x;
  int tid = threadIdx.x, lane = tid & 63, w = tid >> 6;

  int lo = 0, hi = N_NODES;
  while (lo < hi) { int mid = (lo + hi) >> 1; if (batch[mid] < g) lo = mid + 1; else hi = mid; }
  const int start = lo;
  hi = N_NODES;
  while (lo < hi) { int mid = (lo + hi) >> 1; if (batch[mid] < g + 1) lo = mid + 1; else hi = mid; }
  const int end = lo;

  float s = 0.f;
  if (end > start) {
    const int b0 = start >> 6, b1 = ((end - 1) >> 6) + 1;
    for (int b = b0; b < b1; b++) {
      const int q0 = bucket_ptr[b], q1 = bucket_ptr[b + 1];
      const int base = b << 6;
      for (int i = q0 + tid; i < q1; i += 256) {
        unsigned int u = ebuf[i];
        int d = base + (int)(u & 63);
        if (d >= start && d < end) s += z[u >> 6];
      }
    }
  }
#pragma unroll
  for (int off = 32; off; off >>= 1) s += __shfl_down(s, off, 64);
  if (lane == 0) sacc[w] = s;
  __syncthreads();
  if (tid == 0) {
    float v = sacc[0] + sacc[1] + sacc[2] + sacc[3];
    v /= fmaxf((float)(end - start), 1.f);
    out[g] = 1.f / (1.f + expf(-v));
  }
}

// ---------------------------------------------------------------------------
extern "C" void kernel_launch(void* const* d_in, const int* in_sizes, int n_in,
                              void* d_out, int out_size, void* d_ws, size_t ws_size,
                              hipStream_t stream) {
  const float* x     = (const float*)d_in[0];
  const int*   ei    = (const int*)d_in[1];   // [2, E]: src then dst
  const int*   batch = (const int*)d_in[2];
  const float* W1    = (const float*)d_in[3];
  const float* W2    = (const float*)d_in[4];
  const float* Wfc   = (const float*)d_in[5];
  float*       out   = (float*)d_out;

  const int* src = ei;
  const int* dst = ei + N_EDGES;

  // workspace layout (~10.5 MB, all disjoint)
  char* ws = (char*)d_ws;
  unsigned short* h1 = (unsigned short*)(ws);                  // [N,64] bf16
  float* z    = (float*)(ws + (size_t)N_NODES * DIM * 2);      // [N]
  float* w2fc = z + N_NODES;                                   // [64]
  int*   cnt  = (int*)(w2fc + 64);                             // [NCNT]
  int*   partials = cnt + NCNT;                                // [196]
  unsigned int* ebuf = (unsigned int*)(partials + P2_NBLK);    // [E]
  int*   bucket_ptr  = (int*)(ebuf + N_EDGES);                 // [NBKT+1]

  // front chain, each dispatch also crunching a slice of gemm1's 782 tiles
  f_bhist<<<BH_BLK + 1 + T_BHIST, 256, 0, stream>>>(dst, cnt, W2, Wfc, w2fc,
                                                    x, W1, h1);
  f_psum<<<P2_NBLK + T_PSUM, 256, 0, stream>>>(cnt, partials, x, W1, h1);
  f_sblocks<<<P2_NBLK + T_SBLK, 256, 0, stream>>>(cnt, partials, bucket_ptr,
                                                  x, W1, h1);
  f_bscatter<<<BH_BLK + T_BSCAT, 256, 0, stream>>>(src, dst, cnt, ebuf,
                                                   x, W1, h1);

  // per-bucket sort + layer-1 gather + relu + dot(W2@Wfc) -> z[N]
  gather_z_fused<<<NBKT, 1024, 0, stream>>>(h1, ebuf, bucket_ptr, w2fc, z);

  // per-graph edge-sum of z[src], mean, sigmoid
  graph_pool<<<N_GRAPHS, 256, 0, stream>>>(z, ebuf, bucket_ptr, batch, out);
}

// Round 14
// 147.689 us; speedup vs baseline: 1.0810x; 1.0810x over previous
//
#include <hip/hip_runtime.h>
#include <cmath>

#define N_NODES 50000
#define N_EDGES 800000
#define N_FEAT 128
#define DIM 64
#define N_GRAPHS 512
#define GGRID ((N_NODES + 63) / 64)         // 782 gemm1 tiles / buckets
#define NBKT GGRID                          // bucket = dst>>6
#define BH_BLK 128                          // bucket-sort blocks
#define EPB (N_EDGES / BH_BLK)              // 6250 edges per sort block
#define NCNT (NBKT * BH_BLK)                // 100096 count-matrix entries
#define P2_NBLK ((NCNT + 511) / 512)        // 196 scan blocks (512 elems each)
#define BKT_CAP 2048                        // max bucket edges (mean 1024)

// bf16 storage helpers (RNE). Storage-only: all math in fp32.
__device__ __forceinline__ unsigned short f2bf(float f) {
  union { float f; unsigned int u; } v; v.f = f;
  return (unsigned short)((v.u + 0x7FFFu + ((v.u >> 16) & 1u)) >> 16);
}
__device__ __forceinline__ float bf2f(unsigned short u) {
  union { unsigned int u; float f; } v; v.u = (unsigned int)u << 16;
  return v.f;
}

// ---------------------------------------------------------------------------
// dispatch 1: blocks [0,128) bucket histogram of dst>>6 (cnt bucket-major:
// cnt[b*BH_BLK + k]); block 128 = w2fc = W2@Wfc precompute.
__global__ __launch_bounds__(256) void bhist_w2fc(const int* __restrict__ dst,
                                                  int* __restrict__ cnt,
                                                  const float* __restrict__ W2,
                                                  const float* __restrict__ Wfc,
                                                  float* __restrict__ w2fc) {
  if (blockIdx.x == BH_BLK) {
    int k = threadIdx.x;
    if (k < 64) {
      float s = 0.f;
#pragma unroll 8
      for (int j = 0; j < 64; j++) s += W2[k * 64 + j] * Wfc[j];
      w2fc[k] = s;
    }
    return;
  }
  __shared__ int lh[NBKT];
  const int tid = threadIdx.x, k = blockIdx.x;
  for (int i = tid; i < NBKT; i += 256) lh[i] = 0;
  __syncthreads();
  const int base = k * EPB;
  for (int j = tid; j < EPB; j += 256)
    atomicAdd(&lh[dst[base + j] >> 6], 1);
  __syncthreads();
  for (int i = tid; i < NBKT; i += 256) cnt[i * BH_BLK + k] = lh[i];
}

// ---------------------------------------------------------------------------
// dispatch 2: per-512-chunk RAW sums of cnt (196 blocks, pair-indexed).
__global__ __launch_bounds__(256) void f_psum(const int* __restrict__ cnt,
                                              int* __restrict__ partials) {
  __shared__ int ws[4];
  const int tid = threadIdx.x;
  const int2* cnt2 = (const int2*)cnt;
  int idx = blockIdx.x * 256 + tid;                 // pair index
  int v = 0;
  if (idx * 2 < NCNT) { int2 c = cnt2[idx]; v = c.x + c.y; }
#pragma unroll
  for (int off = 32; off; off >>= 1) v += __shfl_down(v, off, 64);
  int lane = tid & 63, w = tid >> 6;
  if (lane == 0) ws[w] = v;
  __syncthreads();
  if (tid == 0) partials[blockIdx.x] = ws[0] + ws[1] + ws[2] + ws[3];
}

// ---------------------------------------------------------------------------
// dispatch 3: block-local scan of 512 cnt elems + redundant LDS scan of the
// 196 raw partials -> in-place exclusive offsets + bucket_ptr. (Folds the
// former scan_partials dispatch; verified correct in R13.)
__global__ __launch_bounds__(256) void f_sblocks(int* __restrict__ cnt,
                                                 const int* __restrict__ partials,
                                                 int* __restrict__ bucket_ptr) {
  __shared__ int buf[256];
  __shared__ int pbuf[256];
  const int tid = threadIdx.x;
  int2* cnt2 = (int2*)cnt;
  const int idx = blockIdx.x * 256 + tid;
  int2 c = make_int2(0, 0);
  if (idx * 2 < NCNT) c = cnt2[idx];
  int s = c.x + c.y;
  buf[tid] = s;
  pbuf[tid] = (tid < P2_NBLK) ? partials[tid] : 0;
  __syncthreads();
  for (int off = 1; off < 256; off <<= 1) {         // inclusive scans
    int t1 = (tid >= off) ? buf[tid - off] : 0;
    int t2 = (tid >= off) ? pbuf[tid - off] : 0;
    __syncthreads();
    buf[tid] += t1;
    pbuf[tid] += t2;
    __syncthreads();
  }
  const int thr_excl = buf[tid] - s;
  const int base = (blockIdx.x > 0) ? pbuf[blockIdx.x - 1] : 0;
  if (idx * 2 < NCNT) {
    int e0 = base + thr_excl;
    cnt2[idx] = make_int2(e0, e0 + c.x);            // exclusive offsets
    int p = idx * 2;
    if ((p & (BH_BLK - 1)) == 0) bucket_ptr[p >> 7] = e0;
    if (p + 1 == NCNT - 1) bucket_ptr[NBKT] = e0 + c.x + c.y;  // == N_EDGES
  }
}

// ---------------------------------------------------------------------------
// GEMM body for gemm1: out[M][64] = A[M][128] @ W[128][64], bf16 output rows.
template<int K>
__device__ __forceinline__ void gemm_body_bf(const float* __restrict__ A,
                                             const float* __restrict__ W,
                                             unsigned short* __restrict__ out,
                                             int M, int row0, int tid,
                                             float* sX, float* sW) {
  const int tx = tid & 15, ty = tid >> 4;
  const int q = tid & 7, r0 = tid >> 3;
  float acc[4][4] = {};

  for (int kb = 0; kb < K; kb += 32) {
    __syncthreads();
    if ((kb & 63) == 0) {
#pragma unroll
      for (int i = 0; i < 16; i++)
        sW[i * 256 + tid] = W[kb * 64 + i * 256 + tid];
    }
#pragma unroll
    for (int rr = 0; rr < 64; rr += 32) {
      int r = r0 + rr;
      int gr = row0 + r;
      float4 v = make_float4(0.f, 0.f, 0.f, 0.f);
      if (gr < M) v = *(const float4*)&A[(size_t)gr * K + kb + q * 4];
      *(float4*)&sX[r * 36 + q * 4] = v;
    }
    __syncthreads();

    const int kw = kb & 63;
#pragma unroll 4
    for (int k = 0; k < 32; k += 4) {
      float4 wv[4];
#pragma unroll
      for (int kk = 0; kk < 4; kk++)
        wv[kk] = *(const float4*)&sW[(kw + k + kk) * 64 + tx * 4];
#pragma unroll
      for (int r = 0; r < 4; r++) {
        float4 xv = *(const float4*)&sX[(ty * 4 + r) * 36 + k];
        const float xs[4] = {xv.x, xv.y, xv.z, xv.w};
#pragma unroll
        for (int kk = 0; kk < 4; kk++) {
          acc[r][0] += xs[kk] * wv[kk].x;
          acc[r][1] += xs[kk] * wv[kk].y;
          acc[r][2] += xs[kk] * wv[kk].z;
          acc[r][3] += xs[kk] * wv[kk].w;
        }
      }
    }
  }

#pragma unroll
  for (int r = 0; r < 4; r++) {
    int gr = row0 + ty * 4 + r;
    if (gr < M) {
      ushort4 u;
      u.x = f2bf(acc[r][0]); u.y = f2bf(acc[r][1]);
      u.z = f2bf(acc[r][2]); u.w = f2bf(acc[r][3]);
      *(ushort4*)&out[(size_t)gr * 64 + tx * 4] = u;
    }
  }
}

// ---------------------------------------------------------------------------
// dispatch 4: blocks [0,GGRID) = gemm1 (x@W1 -> h1 bf16); blocks [GGRID..)
// = bucket-sorted edge scatter (packed (src<<6)|dst_local). The ~20us
// scatter hides under the full 782-tile gemm1 (R11 pairing — do not split).
__global__ __launch_bounds__(256) void gemm1_bscatter(
    const float* __restrict__ x, const float* __restrict__ W1,
    unsigned short* __restrict__ h1, const int* __restrict__ src,
    const int* __restrict__ dst, const int* __restrict__ cnt,
    unsigned int* __restrict__ ebuf) {
  __shared__ float sX[64 * 36];
  __shared__ float sW[64 * 64];
  const int tid = threadIdx.x;
  if (blockIdx.x < GGRID) {
    gemm_body_bf<N_FEAT>(x, W1, h1, N_NODES, blockIdx.x * 64, tid, sX, sW);
  } else {
    int* loff = (int*)sX;                     // 782 ints fit easily
    const int k = blockIdx.x - GGRID;
    for (int i = tid; i < NBKT; i += 256) loff[i] = cnt[i * BH_BLK + k];
    __syncthreads();
    const int base = k * EPB;
    for (int j = tid; j < EPB; j += 256) {
      int e = base + j;
      int d = dst[e];
      int pos = atomicAdd(&loff[d >> 6], 1);
      ebuf[pos] = ((unsigned int)src[e] << 6) | (unsigned int)(d & 63);
    }
  }
}

// ---------------------------------------------------------------------------
// dispatch 5: per-bucket LDS CSR sort + layer-1 gather + relu + dot(w2fc)
// -> z[node]. 782 blocks x 1024 threads (16 waves x 4 nodes).
__global__ __launch_bounds__(1024, 8) void gather_z_fused(
    const unsigned short* __restrict__ h1,
    const unsigned int* __restrict__ ebuf,
    const int* __restrict__ bucket_ptr,
    const float* __restrict__ w2fc,
    float* __restrict__ z) {
  __shared__ int colL[BKT_CAP];
  __shared__ int lstart[64];
  __shared__ int lcur[64];
  __shared__ float sw[64];
  const int tid = threadIdx.x;
  const int b = blockIdx.x;
  const int p0 = bucket_ptr[b];
  int cnt = bucket_ptr[b + 1] - p0;
  if (cnt > BKT_CAP) cnt = BKT_CAP;                 // never triggers

  if (tid < 64) { lstart[tid] = 0; sw[tid] = w2fc[tid]; }
  __syncthreads();
  for (int i = tid; i < cnt; i += 1024)
    atomicAdd(&lstart[ebuf[p0 + i] & 63], 1);
  __syncthreads();
  if (tid < 64) {
    int v = lstart[tid], s = v;
#pragma unroll
    for (int off = 1; off < 64; off <<= 1) {
      int t = __shfl_up(s, off, 64);
      if (tid >= off) s += t;
    }
    lstart[tid] = s - v;
    lcur[tid] = s - v;
  }
  __syncthreads();
  for (int i = tid; i < cnt; i += 1024) {
    unsigned int u = ebuf[p0 + i];
    int pos = atomicAdd(&lcur[u & 63], 1);
    colL[pos] = (int)(u >> 6);
  }
  __syncthreads();

  const int lane = tid & 63, w = tid >> 6;
  const int eo = lane >> 4, qfo = (lane & 15) << 2;
#pragma unroll
  for (int ni = 0; ni < 4; ni++) {
    const int r = ni * 16 + w;
    const int i1 = lcur[r];
    int i = lstart[r];
    float4 acc = make_float4(0.f, 0.f, 0.f, 0.f);
    for (; i + 16 <= i1; i += 16) {
      int s0 = colL[i + eo];
      int s1 = colL[i + 4 + eo];
      int s2 = colL[i + 8 + eo];
      int s3 = colL[i + 12 + eo];
      ushort4 u0 = *(const ushort4*)&h1[(size_t)s0 * 64 + qfo];
      ushort4 u1 = *(const ushort4*)&h1[(size_t)s1 * 64 + qfo];
      ushort4 u2 = *(const ushort4*)&h1[(size_t)s2 * 64 + qfo];
      ushort4 u3 = *(const ushort4*)&h1[(size_t)s3 * 64 + qfo];
      acc.x += (bf2f(u0.x) + bf2f(u1.x)) + (bf2f(u2.x) + bf2f(u3.x));
      acc.y += (bf2f(u0.y) + bf2f(u1.y)) + (bf2f(u2.y) + bf2f(u3.y));
      acc.z += (bf2f(u0.z) + bf2f(u1.z)) + (bf2f(u2.z) + bf2f(u3.z));
      acc.w += (bf2f(u0.w) + bf2f(u1.w)) + (bf2f(u2.w) + bf2f(u3.w));
    }
    for (; i + 4 <= i1; i += 4) {
      int s = colL[i + eo];
      ushort4 u = *(const ushort4*)&h1[(size_t)s * 64 + qfo];
      acc.x += bf2f(u.x); acc.y += bf2f(u.y);
      acc.z += bf2f(u.z); acc.w += bf2f(u.w);
    }
    if (eo < i1 - i) {
      int s = colL[i + eo];
      ushort4 u = *(const ushort4*)&h1[(size_t)s * 64 + qfo];
      acc.x += bf2f(u.x); acc.y += bf2f(u.y);
      acc.z += bf2f(u.z); acc.w += bf2f(u.w);
    }
#pragma unroll
    for (int m = 16; m <= 32; m <<= 1) {            // reduce over eo
      acc.x += __shfl_xor(acc.x, m, 64);
      acc.y += __shfl_xor(acc.y, m, 64);
      acc.z += __shfl_xor(acc.z, m, 64);
      acc.w += __shfl_xor(acc.w, m, 64);
    }
    float p = fmaxf(acc.x, 0.f) * sw[qfo] + fmaxf(acc.y, 0.f) * sw[qfo + 1] +
              fmaxf(acc.z, 0.f) * sw[qfo + 2] + fmaxf(acc.w, 0.f) * sw[qfo + 3];
#pragma unroll
    for (int m = 1; m <= 8; m <<= 1) p += __shfl_xor(p, m, 64);
    int node = b * 64 + r;
    if (lane == 0 && node < N_NODES) z[node] = p;
  }
}

// ---------------------------------------------------------------------------
// dispatch 6: per-graph sum over EDGES whose dst lies in the graph's node
// range of z[src] (layer-2 aggregation collapsed); /count; sigmoid.
__global__ __launch_bounds__(256) void graph_pool(const float* __restrict__ z,
                                                  const unsigned int* __restrict__ ebuf,
                                                  const int* __restrict__ bucket_ptr,
                                                  const int* __restrict__ batch,
                                                  float* __restrict__ out) {
  __shared__ float sacc[4];
  int g = blockIdx.x;
  int tid = threadIdx.x, lane = tid & 63, w = tid >> 6;

  int lo = 0, hi = N_NODES;
  while (lo < hi) { int mid = (lo + hi) >> 1; if (batch[mid] < g) lo = mid + 1; else hi = mid; }
  const int start = lo;
  hi = N_NODES;
  while (lo < hi) { int mid = (lo + hi) >> 1; if (batch[mid] < g + 1) lo = mid + 1; else hi = mid; }
  const int end = lo;

  float s = 0.f;
  if (end > start) {
    const int b0 = start >> 6, b1 = ((end - 1) >> 6) + 1;
    for (int b = b0; b < b1; b++) {
      const int q0 = bucket_ptr[b], q1 = bucket_ptr[b + 1];
      const int base = b << 6;
      for (int i = q0 + tid; i < q1; i += 256) {
        unsigned int u = ebuf[i];
        int d = base + (int)(u & 63);
        if (d >= start && d < end) s += z[u >> 6];
      }
    }
  }
#pragma unroll
  for (int off = 32; off; off >>= 1) s += __shfl_down(s, off, 64);
  if (lane == 0) sacc[w] = s;
  __syncthreads();
  if (tid == 0) {
    float v = sacc[0] + sacc[1] + sacc[2] + sacc[3];
    v /= fmaxf((float)(end - start), 1.f);
    out[g] = 1.f / (1.f + expf(-v));
  }
}

// ---------------------------------------------------------------------------
extern "C" void kernel_launch(void* const* d_in, const int* in_sizes, int n_in,
                              void* d_out, int out_size, void* d_ws, size_t ws_size,
                              hipStream_t stream) {
  const float* x     = (const float*)d_in[0];
  const int*   ei    = (const int*)d_in[1];   // [2, E]: src then dst
  const int*   batch = (const int*)d_in[2];
  const float* W1    = (const float*)d_in[3];
  const float* W2    = (const float*)d_in[4];
  const float* Wfc   = (const float*)d_in[5];
  float*       out   = (float*)d_out;

  const int* src = ei;
  const int* dst = ei + N_EDGES;

  // workspace layout (~10.5 MB, all disjoint)
  char* ws = (char*)d_ws;
  unsigned short* h1 = (unsigned short*)(ws);                  // [N,64] bf16
  float* z    = (float*)(ws + (size_t)N_NODES * DIM * 2);      // [N]
  float* w2fc = z + N_NODES;                                   // [64]
  int*   cnt  = (int*)(w2fc + 64);                             // [NCNT]
  int*   partials = cnt + NCNT;                                // [196]
  unsigned int* ebuf = (unsigned int*)(partials + P2_NBLK);    // [E]
  int*   bucket_ptr  = (int*)(ebuf + N_EDGES);                 // [NBKT+1]

  // CSR front half: bucket histogram (+w2fc) -> raw sums -> fused scan
  bhist_w2fc<<<BH_BLK + 1, 256, 0, stream>>>(dst, cnt, W2, Wfc, w2fc);
  f_psum<<<P2_NBLK, 256, 0, stream>>>(cnt, partials);
  f_sblocks<<<P2_NBLK, 256, 0, stream>>>(cnt, partials, bucket_ptr);

  // gemm1 (h1 = bf16(x@W1)) || bucket-sorted edge scatter (R11 pairing)
  gemm1_bscatter<<<GGRID + BH_BLK, 256, 0, stream>>>(x, W1, h1, src, dst, cnt, ebuf);

  // per-bucket sort + layer-1 gather + relu + dot(W2@Wfc) -> z[N]
  gather_z_fused<<<NBKT, 1024, 0, stream>>>(h1, ebuf, bucket_ptr, w2fc, z);

  // per-graph edge-sum of z[src], mean, sigmoid
  graph_pool<<<N_GRAPHS, 256, 0, stream>>>(z, ebuf, bucket_ptr, batch, out);
}